// Round 1
// baseline (705.217 us; speedup 1.0000x reference)
//
#include <hip/hip_runtime.h>
#include <hip/hip_bf16.h>

#define N_NODES 50000
#define N_EDGES 800000
#define N_GRAPHS 128
#define NB2 391           // 128-node dst buckets == GEMM tiles
#define BCAP 4096         // bucket capacity (validated R12)
#define EPB2 2048         // edges per block in prep partition phase (391 blocks)
#define WORKERS NB2       // barrier participants in layer_kernel

typedef __attribute__((ext_vector_type(8))) short short8;
typedef __attribute__((ext_vector_type(4))) float f32x4;

union B16x8 { uint4 u; short8 s; };

__device__ __forceinline__ unsigned bf16rn(float f) {
    unsigned u = __float_as_uint(f);
    return (u + 0x7FFFu + ((u >> 16) & 1u)) >> 16;
}
__device__ __forceinline__ unsigned packbf2(float a, float b) {
    return bf16rn(a) | (bf16rn(b) << 16);
}
__device__ __forceinline__ float2 unpkbf2(unsigned v) {
    return make_float2(__uint_as_float(v << 16), __uint_as_float(v & 0xFFFF0000u));
}
__device__ __forceinline__ void unpack8(uint4 g, float* f) {
    float2 a = unpkbf2(g.x), b = unpkbf2(g.y), c = unpkbf2(g.z), d = unpkbf2(g.w);
    f[0] = a.x; f[1] = a.y; f[2] = b.x; f[3] = b.y;
    f[4] = c.x; f[5] = c.y; f[6] = d.x; f[7] = d.y;
}

// Device-scope grid barrier. Co-residency of all `expected` arriving blocks is
// guaranteed by __launch_bounds__(256,2) (>=2 blocks/CU -> 512 slots).
__device__ __forceinline__ void grid_barrier(int* bar, int expected) {
    __syncthreads();                      // drains each wave's vmem (writes at L2)
    if (threadIdx.x == 0) {
        __threadfence();                  // agent release: L2 writeback
        __hip_atomic_fetch_add(bar, 1, __ATOMIC_RELEASE, __HIP_MEMORY_SCOPE_AGENT);
        while (__hip_atomic_load(bar, __ATOMIC_ACQUIRE, __HIP_MEMORY_SCOPE_AGENT) < expected)
            __builtin_amdgcn_s_sleep(4);
        __threadfence();                  // agent acquire: L1/L2 invalidate
    }
    __syncthreads();
}

// ---------------- prep: bf16 convert + W transpose + graph starts + edge
// partition -> grid barrier -> per-bucket counting sort  (1 dispatch) --------

__global__ __launch_bounds__(256, 2) void prep_kernel(
    const int* __restrict__ dst, const int* __restrict__ src, const float* __restrict__ w,
    int* __restrict__ cursor, int2* __restrict__ tmp, int E,
    const float* __restrict__ x, unsigned* __restrict__ xb,
    const float* __restrict__ W1, const float* __restrict__ W2,
    unsigned short* __restrict__ Wt, const int* __restrict__ gid,
    int* __restrict__ start, int n, int ngraphs,
    int* __restrict__ bar, int2* __restrict__ row_se, unsigned* __restrict__ pack) {
    __shared__ int lh[NB2];
    __shared__ int lbase[NB2];
    __shared__ int hist[128];
    __shared__ int run[128];
    __shared__ int s[256];
    const int t = threadIdx.x;
    const int gtid = blockIdx.x * 256 + t;
    const int gsz = gridDim.x * 256;

    for (int i = gtid; i < n * 8; i += gsz) {
        float4 a = *(const float4*)(x + (size_t)i * 8);
        float4 b = *(const float4*)(x + (size_t)i * 8 + 4);
        uint4 o;
        o.x = packbf2(a.x, a.y);
        o.y = packbf2(a.z, a.w);
        o.z = packbf2(b.x, b.y);
        o.w = packbf2(b.z, b.w);
        *(uint4*)(xb + (size_t)i * 4) = o;
    }
    for (int i = gtid; i < 8 * 4096; i += gsz) {
        int mat = i >> 12, k = (i >> 6) & 63, nn = i & 63, l = mat >> 1;
        const float* Wsrc = (mat & 1) ? (W2 + l * 4096) : (W1 + l * 4096);
        Wt[(size_t)mat * 4096 + nn * 64 + k] = (unsigned short)bf16rn(Wsrc[k * 64 + nn]);
    }
    for (int i = gtid; i < n; i += gsz) {
        int g = gid[i];
        if (i == 0) {
            for (int q = 0; q <= g; ++q) start[q] = 0;
        } else {
            int p = gid[i - 1];
            if (p != g)
                for (int q = p + 1; q <= g; ++q) start[q] = i;
        }
        if (i == n - 1)
            for (int q = g + 1; q <= ngraphs; ++q) start[q] = n;
    }

    for (int i = t; i < NB2; i += 256) lh[i] = 0;
    __syncthreads();
    int base = blockIdx.x * EPB2;
    int d[EPB2 / 256];
#pragma unroll
    for (int i = 0; i < EPB2 / 256; ++i) {
        int e = base + i * 256 + t;
        d[i] = (e < E) ? dst[e] : -1;
        if (d[i] >= 0) atomicAdd(&lh[d[i] >> 7], 1);
    }
    __syncthreads();
    for (int i = t; i < NB2; i += 256) {
        int v = lh[i];
        if (v) lbase[i] = atomicAdd(&cursor[i], v);
        lh[i] = 0;
    }
    __syncthreads();
#pragma unroll
    for (int i = 0; i < EPB2 / 256; ++i) {
        int e = base + i * 256 + t;
        if (d[i] >= 0) {
            int bb = d[i] >> 7;
            int dl = d[i] & 127;
            int rank = atomicAdd(&lh[bb], 1);
            tmp[(size_t)bb * BCAP + lbase[bb] + rank] =
                make_int2(src[e] | (dl << 16), __float_as_int(w[e]));
        }
    }

    grid_barrier(bar, (int)gridDim.x);

    // ---- sort phase: bucket b = blockIdx.x ----
    const int b = blockIdx.x;
    int cnt = cursor[b];
    if (cnt > BCAP) cnt = BCAP;
    const int2* tb2 = tmp + (size_t)b * BCAP;
    const int gbase = b * BCAP;

    if (t < 128) hist[t] = 0;
    __syncthreads();
    for (int j = t; j < cnt; j += 256) atomicAdd(&hist[(tb2[j].x >> 16) & 127], 1);
    __syncthreads();
    int v = (t < 128) ? hist[t] : 0;
    s[t] = v;
    __syncthreads();
    for (int off = 1; off < 128; off <<= 1) {
        int u2 = (t >= off) ? s[t - off] : 0;
        __syncthreads();
        s[t] += u2;
        __syncthreads();
    }
    if (t < 128) {
        int excl = s[t] - v;
        int node = b * 128 + t;
        if (node < n) row_se[node] = make_int2(gbase + excl, gbase + excl + v);
        run[t] = gbase + excl;
    }
    __syncthreads();
    for (int j = t; j < cnt; j += 256) {
        int2 p = tb2[j];
        int pos = atomicAdd(&run[(p.x >> 16) & 127], 1);
        pack[pos] = (unsigned)(p.x & 0xFFFF) | (bf16rn(__int_as_float(p.y)) << 16);
    }
}

// ---------------- fused GIN layer: agg(+prev outer BN) -> LDS tile -> GEMM1
// -> batch-BN stats -> grid barrier -> BN+ReLU -> GEMM2 -> out + outer stats.
// Extra 128 blocks pool the layer INPUT into score (no barrier participation).

__global__ __launch_bounds__(256, 2) void layer_kernel(
    const unsigned* __restrict__ hb, const unsigned* __restrict__ pack,
    const int2* __restrict__ row_se, const float* __restrict__ eps_arr, const int layer,
    unsigned* __restrict__ outb, const int n,
    const float* __restrict__ stats_prev, const float* __restrict__ g_prev,
    const float* __restrict__ b_prev, const int transform,
    const unsigned short* __restrict__ Wt1, const unsigned short* __restrict__ Wt2,
    const float* __restrict__ bias1, const float* __restrict__ bias2,
    const float* __restrict__ bn_g, const float* __restrict__ bn_b,
    float* __restrict__ stats1, float* __restrict__ stats2, int* __restrict__ bar,
    const int* __restrict__ start, const float* __restrict__ pW,
    const float* __restrict__ pb, float* __restrict__ score) {
    __shared__ float sc[64], sh[64];
    __shared__ float sc2[64], sh2[64];
    __shared__ __align__(16) unsigned short At[128 * 64];   // agg tile, reused as cstage
    __shared__ float rsum[64 * 17], rsq[64 * 17];
    __shared__ float red[16][68];
    __shared__ float pl[64];

    const int t = threadIdx.x;
    if (transform && t < 64) {
        float inv_n = 1.0f / (float)n;
        float mean = stats_prev[t] * inv_n;
        float var = stats_prev[64 + t] * inv_n - mean * mean;
        float s0 = g_prev[t] * rsqrtf(var + 1e-5f);
        sc[t] = s0;
        sh[t] = b_prev[t] - mean * s0;
    }
    __syncthreads();

    if ((int)blockIdx.x >= WORKERS) {
        // ---- pool role: pool layer-INPUT h per graph, add pred head ----
        const int g = blockIdx.x - WORKERS;
        const int r16 = t >> 4;
        const int qq = t & 15;
        const int k0 = qq << 2;
        int i0 = start[g], i1 = start[g + 1];
        float4 ps = make_float4(0.f, 0.f, 0.f, 0.f);
        for (int i = i0 + r16; i < i1; i += 16) {
            uint2 u = *(const uint2*)(hb + (size_t)i * 32 + qq * 2);
            float2 a = unpkbf2(u.x);
            float2 b = unpkbf2(u.y);
            if (transform) {
                a.x = fmaxf(fmaf(a.x, sc[k0 + 0], sh[k0 + 0]), 0.f);
                a.y = fmaxf(fmaf(a.y, sc[k0 + 1], sh[k0 + 1]), 0.f);
                b.x = fmaxf(fmaf(b.x, sc[k0 + 2], sh[k0 + 2]), 0.f);
                b.y = fmaxf(fmaf(b.y, sc[k0 + 3], sh[k0 + 3]), 0.f);
            }
            ps.x += a.x; ps.y += a.y; ps.z += b.x; ps.w += b.y;
        }
        red[r16][k0 + 0] = ps.x;
        red[r16][k0 + 1] = ps.y;
        red[r16][k0 + 2] = ps.z;
        red[r16][k0 + 3] = ps.w;
        __syncthreads();
        if (t < 64) {
            float s0 = 0.f;
#pragma unroll
            for (int r = 0; r < 16; ++r) s0 += red[r][t];
            pl[t] = s0;
        }
        __syncthreads();
        if (t < 16) {
            float s0 = pb[t];
#pragma unroll 8
            for (int dd = 0; dd < 64; ++dd) s0 += pl[dd] * pW[dd * 16 + t];
            score[g * 16 + t] = transform ? (score[g * 16 + t] + s0) : s0;
        }
        return;
    }

    // ================= worker block: bucket b = 128 rows = GEMM tile =========
    const int b = blockIdx.x;
    const int wid = t >> 6;
    const int lane = t & 63;
    const int sl = lane >> 3;   // edge slot 0..7
    const int li = lane & 7;    // 16B column chunk 0..7 (8 bf16)

    // hoisted per-lane prev-BN coefs for cols li*8..li*8+7
    float scv[8], shv[8];
#pragma unroll
    for (int e = 0; e < 8; ++e) {
        scv[e] = transform ? sc[li * 8 + e] : 1.f;
        shv[e] = transform ? sh[li * 8 + e] : 0.f;
    }
    const float e1 = 1.0f + eps_arr[layer];

    // hoist row_se for this wave's 32 nodes into lanes 0..31
    int2 se0 = make_int2(0, 0);
    {
        int idx = b * 128 + wid * 32 + (lane & 31);
        if (lane < 32 && idx < n) se0 = row_se[idx];
    }

    // lookahead pack prefetch for node 0 (first 32 edges, predicated)
    int j0n = __shfl(se0.x, 0), j1n = __shfl(se0.y, 0);
    unsigned pknb[4];
    bool pknv[4];
#pragma unroll
    for (int u = 0; u < 4; ++u) {
        int jj = j0n + u * 8 + sl;
        pknv[u] = jj < j1n;
        pknb[u] = pknv[u] ? pack[jj] : 0u;
    }

    for (int i = 0; i < 32; ++i) {
        const int rl = wid * 32 + i;
        const int node = b * 128 + rl;
        const int j0 = j0n, j1 = j1n;
        unsigned pk[4];
        bool pv[4];
#pragma unroll
        for (int u = 0; u < 4; ++u) { pk[u] = pknb[u]; pv[u] = pknv[u]; }

        // issue up to 32 gathers (predicated -> no wasted traffic)
        uint4 g4[4];
        float wv[4];
#pragma unroll
        for (int u = 0; u < 4; ++u) {
            wv[u] = __uint_as_float(pk[u] & 0xFFFF0000u);
            if (pv[u]) g4[u] = *(const uint4*)(hb + (size_t)(pk[u] & 0xFFFFu) * 32 + li * 4);
        }
        uint4 sv;
        const bool selfok = (sl == 0) && (node < n);
        if (selfok) sv = *(const uint4*)(hb + (size_t)node * 32 + li * 4);

        // prefetch next node's pack while gathers are in flight
        if (i < 31) {
            j0n = __shfl(se0.x, i + 1);
            j1n = __shfl(se0.y, i + 1);
#pragma unroll
            for (int u = 0; u < 4; ++u) {
                int jj = j0n + u * 8 + sl;
                pknv[u] = jj < j1n;
                pknb[u] = pknv[u] ? pack[jj] : 0u;
            }
        }

        float acc[8];
#pragma unroll
        for (int e = 0; e < 8; ++e) acc[e] = 0.f;
        if (selfok) {
            float f[8];
            unpack8(sv, f);
            if (transform) {
#pragma unroll
                for (int e = 0; e < 8; ++e) f[e] = fmaxf(fmaf(f[e], scv[e], shv[e]), 0.f);
            }
#pragma unroll
            for (int e = 0; e < 8; ++e) acc[e] = e1 * f[e];
        }
#pragma unroll
        for (int u = 0; u < 4; ++u) {
            if (pv[u]) {
                float f[8];
                unpack8(g4[u], f);
                if (transform) {
#pragma unroll
                    for (int e = 0; e < 8; ++e) f[e] = fmaxf(fmaf(f[e], scv[e], shv[e]), 0.f);
                }
#pragma unroll
                for (int e = 0; e < 8; ++e) acc[e] += wv[u] * f[e];
            }
        }
        // rare tail: degree > 32
        for (int j = j0 + 32; j < j1; j += 32) {
#pragma unroll
            for (int u = 0; u < 4; ++u) {
                int jj = j + u * 8 + sl;
                if (jj < j1) {
                    unsigned p = pack[jj];
                    float ww = __uint_as_float(p & 0xFFFF0000u);
                    uint4 gg = *(const uint4*)(hb + (size_t)(p & 0xFFFFu) * 32 + li * 4);
                    float f[8];
                    unpack8(gg, f);
                    if (transform) {
#pragma unroll
                        for (int e = 0; e < 8; ++e) f[e] = fmaxf(fmaf(f[e], scv[e], shv[e]), 0.f);
                    }
#pragma unroll
                    for (int e = 0; e < 8; ++e) acc[e] += ww * f[e];
                }
            }
        }
        // reduce across the 8 edge slots
#pragma unroll
        for (int e = 0; e < 8; ++e) {
            acc[e] += __shfl_xor(acc[e], 8);
            acc[e] += __shfl_xor(acc[e], 16);
            acc[e] += __shfl_xor(acc[e], 32);
        }
        if (sl == 0) {
            uint4 o;
            o.x = packbf2(acc[0], acc[1]);
            o.y = packbf2(acc[2], acc[3]);
            o.z = packbf2(acc[4], acc[5]);
            o.w = packbf2(acc[6], acc[7]);
            *(uint4*)(At + rl * 64 + ((li * 8) ^ (((rl >> 2) & 3) << 4))) = o;
        }
    }
    __syncthreads();

    // ---------------- GEMM1: At (swizzled LDS) x W1 ----------------
    const int m = lane & 15;
    const int q = lane >> 4;

    B16x8 bf1[4][2];
#pragma unroll
    for (int tc = 0; tc < 4; ++tc)
#pragma unroll
        for (int kc = 0; kc < 2; ++kc)
            bf1[tc][kc].u = *(const uint4*)(Wt1 + (size_t)(tc * 16 + m) * 64 + kc * 32 + q * 8);

    B16x8 af[2][2];
#pragma unroll
    for (int tr = 0; tr < 2; ++tr) {
        int r = wid * 32 + tr * 16 + m;
        int swz = ((r >> 2) & 3) << 4;
#pragma unroll
        for (int kc = 0; kc < 2; ++kc)
            af[tr][kc].u = *(const uint4*)(At + r * 64 + ((kc * 32 + q * 8) ^ swz));
    }

    f32x4 acc1[2][4];
#pragma unroll
    for (int tr = 0; tr < 2; ++tr)
#pragma unroll
        for (int tc = 0; tc < 4; ++tc) {
            acc1[tr][tc] = (f32x4){0.f, 0.f, 0.f, 0.f};
            acc1[tr][tc] = __builtin_amdgcn_mfma_f32_16x16x32_bf16(af[tr][0].s, bf1[tc][0].s,
                                                                   acc1[tr][tc], 0, 0, 0);
            acc1[tr][tc] = __builtin_amdgcn_mfma_f32_16x16x32_bf16(af[tr][1].s, bf1[tc][1].s,
                                                                   acc1[tr][tc], 0, 0, 0);
        }

    float bc[4];
#pragma unroll
    for (int tc = 0; tc < 4; ++tc) bc[tc] = bias1[tc * 16 + m];

    __syncthreads();   // all fragment reads done before At is reused as cstage

    float psum[4] = {0, 0, 0, 0}, psq[4] = {0, 0, 0, 0};
#pragma unroll
    for (int tr = 0; tr < 2; ++tr)
#pragma unroll
        for (int reg = 0; reg < 4; ++reg) {
            int rl = wid * 32 + tr * 16 + q * 4 + reg;
            int gr = b * 128 + rl;
            int sw = ((rl >> 2) & 3) << 4;
            bool ok = gr < n;
#pragma unroll
            for (int tc = 0; tc < 4; ++tc) {
                float val = acc1[tr][tc][reg] + bc[tc];
                int col = tc * 16 + m;
                At[rl * 64 + (col ^ sw)] = (unsigned short)bf16rn(ok ? val : 0.f);
                if (ok) {
                    psum[tc] += val;
                    psq[tc] += val * val;
                }
            }
        }

    int contrib = wid * 4 + q;
#pragma unroll
    for (int tc = 0; tc < 4; ++tc) {
        int c = tc * 16 + m;
        rsum[c * 17 + contrib] = psum[tc];
        rsq[c * 17 + contrib] = psq[tc];
    }
    __syncthreads();
    if (t < 64) {
        float s0 = 0.f, qq2 = 0.f;
#pragma unroll
        for (int i = 0; i < 16; ++i) {
            s0 += rsum[t * 17 + i];
            qq2 += rsq[t * 17 + i];
        }
        atomicAdd(&stats1[t], s0);
        atomicAdd(&stats1[64 + t], qq2);
    }

    // ---- one hard global dependency: full-batch BN statistics ----
    grid_barrier(bar, WORKERS);

    if (t < 64) {
        float inv_n = 1.0f / (float)n;
        float su = __hip_atomic_load(&stats1[t], __ATOMIC_RELAXED, __HIP_MEMORY_SCOPE_AGENT);
        float sq = __hip_atomic_load(&stats1[64 + t], __ATOMIC_RELAXED, __HIP_MEMORY_SCOPE_AGENT);
        float mean = su * inv_n;
        float var = sq * inv_n - mean * mean;
        float s0 = bn_g[t] * rsqrtf(var + 1e-5f);
        sc2[t] = s0;
        sh2[t] = bn_b[t] - mean * s0;
    }
    __syncthreads();

    // ---------------- GEMM2: BN+ReLU(cstage) x W2 ----------------
    B16x8 bf2[4][2];
#pragma unroll
    for (int tc = 0; tc < 4; ++tc)
#pragma unroll
        for (int kc = 0; kc < 2; ++kc)
            bf2[tc][kc].u = *(const uint4*)(Wt2 + (size_t)(tc * 16 + m) * 64 + kc * 32 + q * 8);

    B16x8 af2[2][2];
#pragma unroll
    for (int tr = 0; tr < 2; ++tr) {
        int r = wid * 32 + tr * 16 + m;
        int swz = ((r >> 2) & 3) << 4;
#pragma unroll
        for (int kc = 0; kc < 2; ++kc)
            af2[tr][kc].u = *(const uint4*)(At + r * 64 + ((kc * 32 + q * 8) ^ swz));
    }
    {
        int k0base = q * 8;
#pragma unroll
        for (int tr = 0; tr < 2; ++tr)
#pragma unroll
            for (int kc = 0; kc < 2; ++kc) {
                int k0 = kc * 32 + k0base;
                float4 s0 = *(const float4*)(sc2 + k0);
                float4 s1 = *(const float4*)(sc2 + k0 + 4);
                float4 h0 = *(const float4*)(sh2 + k0);
                float4 h1 = *(const float4*)(sh2 + k0 + 4);
                uint4 uu = af2[tr][kc].u;
                float2 p0 = unpkbf2(uu.x), p1 = unpkbf2(uu.y);
                float2 p2 = unpkbf2(uu.z), p3 = unpkbf2(uu.w);
                p0.x = fmaxf(fmaf(p0.x, s0.x, h0.x), 0.f);
                p0.y = fmaxf(fmaf(p0.y, s0.y, h0.y), 0.f);
                p1.x = fmaxf(fmaf(p1.x, s0.z, h0.z), 0.f);
                p1.y = fmaxf(fmaf(p1.y, s0.w, h0.w), 0.f);
                p2.x = fmaxf(fmaf(p2.x, s1.x, h1.x), 0.f);
                p2.y = fmaxf(fmaf(p2.y, s1.y, h1.y), 0.f);
                p3.x = fmaxf(fmaf(p3.x, s1.z, h1.z), 0.f);
                p3.y = fmaxf(fmaf(p3.y, s1.w, h1.w), 0.f);
                uu.x = packbf2(p0.x, p0.y);
                uu.y = packbf2(p1.x, p1.y);
                uu.z = packbf2(p2.x, p2.y);
                uu.w = packbf2(p3.x, p3.y);
                af2[tr][kc].u = uu;
            }
    }

    f32x4 acc2[2][4];
#pragma unroll
    for (int tr = 0; tr < 2; ++tr)
#pragma unroll
        for (int tc = 0; tc < 4; ++tc) {
            acc2[tr][tc] = (f32x4){0.f, 0.f, 0.f, 0.f};
            acc2[tr][tc] = __builtin_amdgcn_mfma_f32_16x16x32_bf16(af2[tr][0].s, bf2[tc][0].s,
                                                                   acc2[tr][tc], 0, 0, 0);
            acc2[tr][tc] = __builtin_amdgcn_mfma_f32_16x16x32_bf16(af2[tr][1].s, bf2[tc][1].s,
                                                                   acc2[tr][tc], 0, 0, 0);
        }

    float bc2[4];
#pragma unroll
    for (int tc = 0; tc < 4; ++tc) bc2[tc] = bias2[tc * 16 + m];

    __syncthreads();   // af2 reads done before At is overwritten again

    float psum2[4] = {0, 0, 0, 0}, psq2[4] = {0, 0, 0, 0};
#pragma unroll
    for (int tr = 0; tr < 2; ++tr)
#pragma unroll
        for (int reg = 0; reg < 4; ++reg) {
            int rl = wid * 32 + tr * 16 + q * 4 + reg;
            int gr = b * 128 + rl;
            int sw = ((rl >> 2) & 3) << 4;
            bool ok = gr < n;
#pragma unroll
            for (int tc = 0; tc < 4; ++tc) {
                float val = acc2[tr][tc][reg] + bc2[tc];
                int col = tc * 16 + m;
                At[rl * 64 + (col ^ sw)] = (unsigned short)bf16rn(ok ? val : 0.f);
                if (ok) {
                    psum2[tc] += val;
                    psq2[tc] += val * val;
                }
            }
        }
#pragma unroll
    for (int tc = 0; tc < 4; ++tc) {
        int c = tc * 16 + m;
        rsum[c * 17 + contrib] = psum2[tc];
        rsq[c * 17 + contrib] = psq2[tc];
    }
    __syncthreads();

#pragma unroll
    for (int rep = 0; rep < 4; ++rep) {
        int idx = rep * 256 + t;
        int rl = idx >> 3;
        int k = idx & 7;
        int gr = b * 128 + rl;
        if (gr < n) {
            int klds = k ^ (((rl >> 2) & 3) << 1);
            uint4 v = *(const uint4*)(At + rl * 64 + klds * 8);
            *(uint4*)(outb + (size_t)gr * 32 + k * 4) = v;
        }
    }

    if (t < 64) {
        float s0 = 0.f, qq2 = 0.f;
#pragma unroll
        for (int i = 0; i < 16; ++i) {
            s0 += rsum[t * 17 + i];
            qq2 += rsq[t * 17 + i];
        }
        atomicAdd(&stats2[t], s0);
        atomicAdd(&stats2[64 + t], qq2);
    }
}

// ---------------- standalone pool+score (final layer only) ----------------

__global__ __launch_bounds__(256) void pool_score_kernel(const unsigned* __restrict__ hb,
                                                         const int* __restrict__ start,
                                                         const float* __restrict__ pW,
                                                         const float* __restrict__ pb,
                                                         float* __restrict__ score,
                                                         const float* __restrict__ stats,
                                                         const float* __restrict__ gamma,
                                                         const float* __restrict__ beta,
                                                         int n, int mode) {
    __shared__ float red[16][68];
    __shared__ float sc[64], sh[64], pl[64];
    const int t = threadIdx.x;
    const int g = blockIdx.x;
    if (mode && t < 64) {
        float inv_n = 1.0f / (float)n;
        float mean = stats[t] * inv_n;
        float var = stats[64 + t] * inv_n - mean * mean;
        float s = gamma[t] * rsqrtf(var + 1e-5f);
        sc[t] = s;
        sh[t] = beta[t] - mean * s;
    }
    __syncthreads();

    const int r16 = t >> 4;
    const int qq = t & 15;
    const int k0 = qq << 2;
    int i0 = start[g], i1 = start[g + 1];
    float4 ps = make_float4(0.f, 0.f, 0.f, 0.f);
    for (int i = i0 + r16; i < i1; i += 16) {
        uint2 u = *(const uint2*)(hb + (size_t)i * 32 + qq * 2);
        float2 a = unpkbf2(u.x);
        float2 b = unpkbf2(u.y);
        if (mode) {
            a.x = fmaxf(fmaf(a.x, sc[k0 + 0], sh[k0 + 0]), 0.f);
            a.y = fmaxf(fmaf(a.y, sc[k0 + 1], sh[k0 + 1]), 0.f);
            b.x = fmaxf(fmaf(b.x, sc[k0 + 2], sh[k0 + 2]), 0.f);
            b.y = fmaxf(fmaf(b.y, sc[k0 + 3], sh[k0 + 3]), 0.f);
        }
        ps.x += a.x; ps.y += a.y; ps.z += b.x; ps.w += b.y;
    }
    red[r16][k0 + 0] = ps.x;
    red[r16][k0 + 1] = ps.y;
    red[r16][k0 + 2] = ps.z;
    red[r16][k0 + 3] = ps.w;
    __syncthreads();
    if (t < 64) {
        float s = 0.f;
#pragma unroll
        for (int r = 0; r < 16; ++r) s += red[r][t];
        pl[t] = s;
    }
    __syncthreads();
    if (t < 16) {
        float s = pb[t];
#pragma unroll 8
        for (int d = 0; d < 64; ++d) s += pl[d] * pW[d * 16 + t];
        score[g * 16 + t] = mode ? (score[g * 16 + t] + s) : s;
    }
}

// ---------------- host ----------------

extern "C" void kernel_launch(void* const* d_in, const int* in_sizes, int n_in,
                              void* d_out, int out_size, void* d_ws, size_t ws_size,
                              hipStream_t stream) {
    const float* x = (const float*)d_in[0];
    const float* w = (const float*)d_in[1];
    const int* src = (const int*)d_in[2];
    const int* dst = (const int*)d_in[3];
    const int* gid = (const int*)d_in[4];
    const float* eps = (const float*)d_in[5];
    const float* W1 = (const float*)d_in[6];
    const float* b1 = (const float*)d_in[7];
    const float* bng = (const float*)d_in[8];
    const float* bnb = (const float*)d_in[9];
    const float* W2 = (const float*)d_in[10];
    const float* b2 = (const float*)d_in[11];
    const float* og = (const float*)d_in[12];
    const float* ob = (const float*)d_in[13];
    const float* pW = (const float*)d_in[14];
    const float* pb = (const float*)d_in[15];
    float* out = (float*)d_out;

    const int N = N_NODES, E = N_EDGES, G = N_GRAPHS;

    unsigned* base = (unsigned*)d_ws;
    unsigned* xb = base;                            // N*32 uints
    unsigned* HA = xb + (size_t)N * 32;             // N*32
    unsigned* HB = HA + (size_t)N * 32;             // N*32
    float* stats = (float*)(HB + (size_t)N * 32);   // 1024 f32 (zeroed)
    int* cursor = (int*)(stats + 1024);             // NB2+1 ints (zeroed)
    int* bar = cursor + NB2 + 1;                    // 8 ints (zeroed): prep + 4 layers
    int* start = bar + 8;                           // 132 ints
    int2* row_se = (int2*)(start + 132);            // N+8 int2
    unsigned short* Wt = (unsigned short*)(row_se + N + 8);   // 8*4096 bf16
    int2* tmp = (int2*)(Wt + 8 * 4096);             // NB2*BCAP int2 = 12.8 MB
    unsigned* pack = (unsigned*)(tmp + (size_t)NB2 * BCAP);   // NB2*BCAP uint

    hipMemsetAsync(stats, 0, (size_t)(1024 + NB2 + 1 + 8) * sizeof(float), stream);

    hipLaunchKernelGGL(prep_kernel, dim3(NB2), dim3(256), 0, stream, dst, src, w, cursor,
                       tmp, E, x, xb, W1, W2, Wt, gid, start, N, G, bar, row_se, pack);

    unsigned* bufs[2] = {HA, HB};
    unsigned* cur = xb;
    for (int l = 0; l < 4; ++l) {
        unsigned* nxt = bufs[l & 1];
        const float* tp = l ? stats + (l - 1) * 256 + 128 : nullptr;
        const float* tg = l ? og + (l - 1) * 64 : nullptr;
        const float* tb = l ? ob + (l - 1) * 64 : nullptr;
        hipLaunchKernelGGL(layer_kernel, dim3(WORKERS + G), dim3(256), 0, stream, cur, pack,
                           row_se, eps, l, nxt, N, tp, tg, tb, l ? 1 : 0,
                           Wt + (size_t)(2 * l) * 4096, Wt + (size_t)(2 * l + 1) * 4096,
                           b1 + l * 64, b2 + l * 64, bng + l * 64, bnb + l * 64,
                           stats + l * 256, stats + l * 256 + 128, bar + 1 + l, start,
                           pW + (size_t)l * 1024, pb + l * 16, out);
        cur = nxt;
    }
    // final pool of h_3 with layer-3 outer BN -> score[pW_4]
    hipLaunchKernelGGL(pool_score_kernel, dim3(G), dim3(256), 0, stream, cur, start,
                       pW + 4 * 1024, pb + 4 * 16, out, stats + 3 * 256 + 128, og + 3 * 64,
                       ob + 3 * 64, N, 1);
}